// Round 9
// baseline (1261.482 us; speedup 1.0000x reference)
//
#include <hip/hip_runtime.h>
#include <stdint.h>

typedef unsigned int u32;
typedef unsigned long long u64;
typedef unsigned short u16b;
typedef __attribute__((ext_vector_type(8))) short short8;   // 8 bf16 = 4 VGPR (MFMA A/B frag)
typedef __attribute__((ext_vector_type(4))) float v4f;      // MFMA C/D frag

constexpr int NP = 16384;   // points per batch
// ---- fixed float-region offsets (in floats) ----
constexpr int W0T = 0;        // [8][64]
constexpr int W1T = 512;      // [64][64]
constexpr int W2T = 4608;     // [64][64]
constexpr int W3T = 8704;     // [64][128]
constexpr int B0F = 16896, B1F = 16960, B2F = 17024, B3F = 17088, B4F = 17216;
constexpr int GFO = 18240;    // gf  [16][1024]
constexpr int GCFO = 34624;   // gcf [4][1024]
constexpr int OF1O = 38720;   // of1 [16][512]
constexpr int GR1O = 46912;   // gr1 [512]
constexpr int FIXED_FLOATS = 47424;
constexpr u32 FIXED_BYTES = FIXED_FLOATS * 4;   // 189696 B

struct __align__(16) f4 { float x, y, z, w; };

__device__ __forceinline__ u16b f2bf(float f){
  u32 u = __float_as_uint(f);
  return (u16b)((u + 0x7FFFu + ((u >> 16) & 1u)) >> 16);   // RNE
}
__device__ __forceinline__ float bfu(u16b h){ return __uint_as_float(((u32)h) << 16); }

// exact-cascade 3-way bf16 split: x ~= hi+mid+lo to ~27 bits
__device__ __forceinline__ void split3(float x, u16b& h, u16b& m, u16b& l){
  h = f2bf(x);           float r1 = x - bfu(h);
  m = f2bf(r1);          float r2 = r1 - bfu(m);
  l = f2bf(r2);
}

__device__ __forceinline__ void fma4(f4& c, float s, const f4& a){
  c.x = fmaf(s, a.x, c.x); c.y = fmaf(s, a.y, c.y);
  c.z = fmaf(s, a.z, c.z); c.w = fmaf(s, a.w, c.w);
}

// ---------------- prep: transpose L0-3 weights; split+frag-pack W5 to bf16x3 ----------------
// Wb layout (bf16): [s][kc][nt][lane][j]  addr = s*131072 + kc*32768 + nt*512 + L*8 + j
__global__ __launch_bounds__(256) void k_prep(
    const float* __restrict__ wl0, const float* __restrict__ wl1, const float* __restrict__ wl2,
    const float* __restrict__ wl3, const float* __restrict__ wl4,
    const float* __restrict__ bl0, const float* __restrict__ bl1, const float* __restrict__ bl2,
    const float* __restrict__ bl3, const float* __restrict__ bl4,
    float* __restrict__ wsf, u32 pmax_off, u32 gmax_off, u32 wb_off, int P, int G)
{
  int tid = blockIdx.x * 256 + threadIdx.x;            // grid 1024 -> 262144 threads
  u64* pmax = (u64*)((char*)wsf + pmax_off);
  u32* gmax = (u32*)((char*)wsf + gmax_off);
  if (tid < P * 16384) pmax[tid] = 0ull;
  if (tid < G * 4096)  gmax[tid] = 0u;
  if (tid < 131072){                                   // W5 split -> Wb
    int ch = tid >> 7, k = tid & 127;
    float x = wl4[tid];                                // wl4[ch*128 + k]
    u16b h, m, l; split3(x, h, m, l);
    int kc = k >> 5, q = (k >> 3) & 3, j = k & 7, nt = ch >> 4;
    u32 base = (u32)kc*32768u + (u32)nt*512u + (u32)(((ch & 15) | (q << 4)) * 8 + j);
    u16b* wb = (u16b*)((char*)wsf + wb_off);
    wb[base] = h; wb[131072u + base] = m; wb[262144u + base] = l;
  }
  if (tid < 512){ int k = tid >> 6, o = tid & 63;
    wsf[W0T + tid] = (k < 7) ? wl0[o*7 + k] : 0.f; }
  if (tid < 4096){ int k = tid >> 6, o = tid & 63;  wsf[W1T + tid] = wl1[o*64 + k]; }
  if (tid < 4096){ int k = tid >> 6, o = tid & 63;  wsf[W2T + tid] = wl2[o*64 + k]; }
  if (tid < 8192){ int k = tid >> 7, o = tid & 127; wsf[W3T + tid] = wl3[o*64 + k]; }
  if (tid < 64)   wsf[B0F + tid] = bl0[tid];
  if (tid < 64)   wsf[B1F + tid] = bl1[tid];
  if (tid < 64)   wsf[B2F + tid] = bl2[tid];
  if (tid < 128)  wsf[B3F + tid] = bl3[tid];
  if (tid < 1024) wsf[B4F + tid] = bl4[tid];
}

// 4pt x 4ch micro-tile for layers 0..3 (acts from LDS, weights from L2-resident ws)
template<int K, int OSTR>
__device__ __forceinline__ void gemm4(const float* Ain, const float* __restrict__ Wt,
                                      int pt4, int o4, f4* acc)
{
  #pragma unroll
  for (int oi = 0; oi < 4; ++oi) acc[oi] = f4{0.f,0.f,0.f,0.f};
  #pragma unroll 4
  for (int k = 0; k < K; ++k){
    f4 a = *(const f4*)(Ain + k*64 + pt4);
    f4 w = *(const f4*)(Wt + k*OSTR + o4);
    fma4(acc[0], w.x, a); fma4(acc[1], w.y, a);
    fma4(acc[2], w.z, a); fma4(acc[3], w.w, a);
  }
}

__device__ __forceinline__ void epi4(f4* acc, const float* __restrict__ bias,
                                     int o4, float* out, int pt4)
{
  #pragma unroll
  for (int oi = 0; oi < 4; ++oi){
    float bb = bias[o4 + oi];
    f4 v = acc[oi];
    v.x = fmaxf(v.x + bb, 0.f); v.y = fmaxf(v.y + bb, 0.f);
    v.z = fmaxf(v.z + bb, 0.f); v.w = fmaxf(v.w + bb, 0.f);
    *(f4*)(out + (o4 + oi)*64 + pt4) = v;
  }
}

// split3 + frag-store of one L3 output half into F4 (LDS). Named-array ref at each
// call site (NO dynamic pointer select — round 8's select forced both acc arrays to
// scratch: FETCH 7MB->2.45GB). Slot swizzle S = Lf ^ m (m varies inside the 16-lane
// write group -> 8 banks x 2 lanes = conflict-free; reads use L ^ m, a lane bijection).
template<int H>
__device__ __forceinline__ void storeF4(u16b* F4, const f4 (&acc)[4],
                                        int o4, int pt4, const float* __restrict__ wsf)
{
  const int kbase = o4 + 64*H;
  const int kc = kbase >> 5, q = (kbase >> 3) & 3, j0 = kbase & 7;
  #pragma unroll
  for (int jj = 0; jj < 4; ++jj){
    int pt = pt4 + jj;
    int m = pt >> 4, Lf = (pt & 15) | (q << 4);
    int SLf = Lf ^ m;                       // ^m swizzle (bank-spreading)
    u16b hh[4], mm[4], ll[4];
    #pragma unroll
    for (int oi = 0; oi < 4; ++oi){
      float v = fmaxf(((const float*)&acc[oi])[jj] + wsf[B3F + kbase + oi], 0.f);
      split3(v, hh[oi], mm[oi], ll[oi]);
    }
    u32 base = (u32)((m*4 + kc)*512 + SLf*8 + j0);
    #pragma unroll
    for (int s = 0; s < 3; ++s){
      const u16b* src = (s == 0) ? hh : (s == 1) ? mm : ll;
      uint2 pk;
      pk.x = (u32)src[0] | ((u32)src[1] << 16);
      pk.y = (u32)src[2] | ((u32)src[3] << 16);
      *(uint2*)(F4 + (u32)s*8192u + base) = pk;
    }
  }
}

// ---------------- fused local MLP: L0-3 fp32 VALU, L4 bf16-split3 MFMA ----------------
// Single 48 KB LDS buffer, region-multiplexed:
//   A0 [0,448)f + gmS @448f | A1/A3 @512f (16 KB) | A2 @4608f (16 KB) | F4 = whole buf (48 KB)
// 48 KB -> 3 blocks/CU (12 waves).
__global__ __launch_bounds__(256, 3) void k_main(const float* __restrict__ pts,
    const float* __restrict__ wsf,
    const u16b* __restrict__ wb,            // Wb split weights (global, L2-resident)
    u64* __restrict__ pmax, u32* __restrict__ gmax,
    int pmask, int gmask)
{
  __shared__ __align__(16) float sB[12288];    // 49152 B
  const int t = threadIdx.x;
  const int b = blockIdx.x >> 8;
  const int tile = blockIdx.x & 255;
  const int n0 = tile * 64;
  const int ptg = t & 15, pt4 = ptg << 2;
  const int chg = t >> 4;
  const int o4 = chg << 2;
  const int w = t >> 6;            // wave id 0..3
  const int L = t & 63;
  const int qb = (L >> 4) << 2;    // my D-row quad base

  u64* gmS = (u64*)(sB + 448);
  if (t < 4) gmS[t] = 0ull;
  for (int e = t; e < 7*64; e += 256)
    sB[e] = pts[(b*7 + (e >> 6))*NP + n0 + (e & 63)];
  __syncthreads();   // s1

  // per-point group id (argmax ch 3..6, first occurrence) -> 64-bit masks
  if (t < 64){
    float v = sB[3*64 + t]; int gi = 0;
    float u1 = sB[4*64 + t]; if (u1 > v){ v = u1; gi = 1; }
    float u2 = sB[5*64 + t]; if (u2 > v){ v = u2; gi = 2; }
    float u3 = sB[6*64 + t]; if (u3 > v){ v = u3; gi = 3; }
    atomicOr(&gmS[gi], 1ull << t);
  }

  f4 acc4[4];
  gemm4<7,64>(sB, wsf + W0T, pt4, o4, acc4);        // L0 reads A0 @0
  epi4(acc4, wsf + B0F, o4, sB + 512, pt4);         // A1 @512 (disjoint from A0)
  __syncthreads();   // s2 (A1 ready + masks done)

  // ggpack: 2-bit group id for each of my 16 D-slots (i = m*4+r -> pt = m*16+qb+r)
  u32 g1lo = (u32)gmS[1], g1hi = (u32)(gmS[1] >> 32);
  u32 g2lo = (u32)gmS[2], g2hi = (u32)(gmS[2] >> 32);
  u32 g3lo = (u32)gmS[3], g3hi = (u32)(gmS[3] >> 32);
  u32 ggpack = 0;
  #pragma unroll
  for (int i = 0; i < 16; ++i){
    int m = i >> 2, r = i & 3;
    int sh = ((m & 1) << 4) + qb + r;          // pt&31
    u32 b1 = ((m < 2 ? g1lo : g1hi) >> sh) & 1u;
    u32 b2 = ((m < 2 ? g2lo : g2hi) >> sh) & 1u;
    u32 b3 = ((m < 2 ? g3lo : g3hi) >> sh) & 1u;
    u32 g = b1 + (b2 << 1) + (b3 << 1) + b3;   // 0..3, one-hot source
    ggpack |= g << (2*i);
  }

  gemm4<64,64>(sB + 512, wsf + W1T, pt4, o4, acc4);  epi4(acc4, wsf + B1F, o4, sB + 4608, pt4);
  __syncthreads();   // s3 (A2 @4608)
  gemm4<64,64>(sB + 4608, wsf + W2T, pt4, o4, acc4); epi4(acc4, wsf + B2F, o4, sB + 512, pt4);
  __syncthreads();   // s4 (A3 @512)

  // L3: both halves into named register arrays (A3 stays readable), then barrier
  f4 acc4b[4];
  gemm4<64,128>(sB + 512, wsf + W3T, pt4, o4, acc4);        // ch o4..o4+3
  gemm4<64,128>(sB + 512, wsf + W3T, pt4, o4 + 64, acc4b);  // ch o4+64..
  __syncthreads();   // s5 (all A3 reads complete; F4 may overwrite everything)

  u16b* F4 = (u16b*)sB;   // [s][frag=m*4+kc][slot][j] : 3*16*64*8 bf16 = 48 KB
  storeF4<0>(F4, acc4,  o4, pt4, wsf);
  storeF4<1>(F4, acc4b, o4, pt4, wsf);
  __syncthreads();   // s6 (F4 ready)

  u64* pslot = pmax + (size_t)(tile & pmask)*(16*1024) + b*1024;
  u32* gslot = gmax + (size_t)(tile & gmask)*4096;
  const char* wbc = (const char*)wb;
  const u32 bvo = (u32)L * 16u;

  // ---- L4: 16 N-tiles/wave; 6-term split-3 MFMA; B-frags software-pipelined ----
  short8 bh, bm, bl;
  {
    u32 bofs = ((u32)(w << 4)) * 1024u + bvo;        // (nt = w*16, kc = 0)
    bh = *(const short8*)(wbc +           bofs);
    bm = *(const short8*)(wbc + 262144u + bofs);
    bl = *(const short8*)(wbc + 524288u + bofs);
  }
  for (int nti = 0; nti < 16; ++nti){
    const int nt = (w << 4) + nti;
    float bias = wsf[B4F + (nt << 4) + (L & 15)];    // issue early
    v4f D[4];
    #pragma unroll
    for (int m = 0; m < 4; ++m) D[m] = (v4f)(0.f);
    #pragma unroll
    for (int kc = 0; kc < 4; ++kc){
      short8 cbh = bh, cbm = bm, cbl = bl;
      // prefetch next stage (kc+1, wrapping to next nt; tail over-reads stay in Wb)
      {
        int knext = (kc == 3) ? 0 : kc + 1;
        int ntn   = (kc == 3) ? nt + 1 : nt;
        u32 bofs = (u32)knext*65536u + (u32)ntn*1024u + bvo;
        bh = *(const short8*)(wbc +           bofs);
        bm = *(const short8*)(wbc + 262144u + bofs);
        bl = *(const short8*)(wbc + 524288u + bofs);
      }
      #pragma unroll
      for (int m = 0; m < 4; ++m){
        const u16b* fb = F4 + (u32)((m*4 + kc)*512 + ((L ^ m) << 3));   // ^m swizzle
        short8 a0 = *(const short8*)(fb);
        short8 a1 = *(const short8*)(fb + 8192);
        short8 a2 = *(const short8*)(fb + 16384);
        D[m] = __builtin_amdgcn_mfma_f32_16x16x32_bf16(a0, cbh, D[m], 0, 0, 0);
        D[m] = __builtin_amdgcn_mfma_f32_16x16x32_bf16(a0, cbm, D[m], 0, 0, 0);
        D[m] = __builtin_amdgcn_mfma_f32_16x16x32_bf16(a1, cbh, D[m], 0, 0, 0);
        D[m] = __builtin_amdgcn_mfma_f32_16x16x32_bf16(a0, cbl, D[m], 0, 0, 0);
        D[m] = __builtin_amdgcn_mfma_f32_16x16x32_bf16(a1, cbm, D[m], 0, 0, 0);
        D[m] = __builtin_amdgcn_mfma_f32_16x16x32_bf16(a2, cbh, D[m], 0, 0, 0);
      }
    }
    // epilogue: bias+relu, per-lane argmax over 16 slots, group-masked maxes
    float mx = 0.f; int mi = 0;
    float gm0 = 0.f, gm1 = 0.f, gm2 = 0.f, gm3 = 0.f;
    #pragma unroll
    for (int m = 0; m < 4; ++m){
      #pragma unroll
      for (int r = 0; r < 4; ++r){
        int i = m*4 + r;
        float v = fmaxf(D[m][r] + bias, 0.f);
        int pidx = n0 + m*16 + qb + r;
        if (i == 0){ mx = v; mi = pidx; }
        else if (v > mx){ mx = v; mi = pidx; }
        u32 g = (ggpack >> (2*i)) & 3u;
        gm0 = fmaxf(gm0, (g == 0u) ? v : 0.f);
        gm1 = fmaxf(gm1, (g == 1u) ? v : 0.f);
        gm2 = fmaxf(gm2, (g == 2u) ? v : 0.f);
        gm3 = fmaxf(gm3, (g == 3u) ? v : 0.f);
      }
    }
    #pragma unroll
    for (int s = 16; s <= 32; s <<= 1){
      float m2 = __shfl_xor(mx, s);
      int  i2  = __shfl_xor(mi, s);
      if (m2 > mx || (m2 == mx && i2 < mi)){ mx = m2; mi = i2; }
      gm0 = fmaxf(gm0, __shfl_xor(gm0, s));
      gm1 = fmaxf(gm1, __shfl_xor(gm1, s));
      gm2 = fmaxf(gm2, __shfl_xor(gm2, s));
      gm3 = fmaxf(gm3, __shfl_xor(gm3, s));
    }
    if (L < 16){
      int ch = (nt << 4) + L;
      u64 pk = ((u64)__float_as_uint(mx) << 32) | (u64)(0xFFFFFFFFu - (u32)mi);
      atomicMax(pslot + ch, pk);
      if (gm0 > 0.f) atomicMax(gslot + ch,        __float_as_uint(gm0));
      if (gm1 > 0.f) atomicMax(gslot + 1024 + ch, __float_as_uint(gm1));
      if (gm2 > 0.f) atomicMax(gslot + 2048 + ch, __float_as_uint(gm2));
      if (gm3 > 0.f) atomicMax(gslot + 3072 + ch, __float_as_uint(gm3));
    }
  }
}

// ---------------- fold slots; emit max_indices (fp32) + gf + gcf ----------------
__global__ __launch_bounds__(256) void k_reduce(float* __restrict__ wsf, float* __restrict__ out,
                                                u32 pmax_off, u32 gmax_off, int P, int G)
{
  int e = blockIdx.x * 256 + threadIdx.x;          // grid 80 -> 20480
  u64* pmax = (u64*)((char*)wsf + pmax_off);
  u32* gmax = (u32*)((char*)wsf + gmax_off);
  if (e < 16384){
    u64 m = 0ull;
    for (int s = 0; s < P; ++s){ u64 v = pmax[s*16384 + e]; if (v > m) m = v; }
    float val = __uint_as_float((u32)(m >> 32));
    u32 idx = 0xFFFFFFFFu - (u32)(m & 0xFFFFFFFFull);
    wsf[GFO + e] = val;
    out[4096 + e] = (float)idx;                    // max_indices, fp32
  } else if (e < 20480){
    int e2 = e - 16384;
    u32 mg = 0u;
    for (int s = 0; s < G; ++s){ u32 v = gmax[s*4096 + e2]; if (v > mg) mg = v; }
    wsf[GCFO + e2] = __uint_as_float(mg);
  }
}

// ---------------- small MLPs: one wave per dot product ----------------
__global__ __launch_bounds__(256) void k_mlp1(float* __restrict__ wsf,
    const float* __restrict__ wg0, const float* __restrict__ bg0,
    const float* __restrict__ wgr0, const float* __restrict__ bgr0)
{
  int wid = (blockIdx.x * 256 + threadIdx.x) >> 6;   // grid 2176 -> 8704 waves
  int lane = threadIdx.x & 63;
  if (wid < 8192){                                   // of1 = relu(gf @ wg0^T + bg0)
    int b = wid >> 9, o = wid & 511;
    const float* gf = wsf + GFO + b*1024;
    float s = 0.f;
    #pragma unroll
    for (int i = 0; i < 16; ++i){ int k = lane + (i << 6); s = fmaf(gf[k], wg0[o*1024 + k], s); }
    for (int off = 32; off; off >>= 1) s += __shfl_down(s, off);
    if (lane == 0) wsf[OF1O + b*512 + o] = fmaxf(s + bg0[o], 0.f);
  } else if (wid < 8704){                            // gr1 = relu(gcf @ wgr0^T + bgr0)
    int o = wid - 8192;
    const float* gcf = wsf + GCFO;
    float s = 0.f;
    #pragma unroll 8
    for (int i = 0; i < 64; ++i){ int k = lane + (i << 6); s = fmaf(gcf[k], wgr0[o*4096 + k], s); }
    for (int off = 32; off; off >>= 1) s += __shfl_down(s, off);
    if (lane == 0) wsf[GR1O + o] = fmaxf(s + bgr0[o], 0.f);
  }
}

__global__ __launch_bounds__(256) void k_mlp2(const float* __restrict__ wsf,
    const float* __restrict__ wg1, const float* __restrict__ bg1,
    const float* __restrict__ wgr1, const float* __restrict__ bgr1,
    float* __restrict__ out)
{
  int wid = (blockIdx.x * 256 + threadIdx.x) >> 6;   // grid 544 -> 2176 waves
  int lane = threadIdx.x & 63;
  if (wid < 2048){                                   // output_feature -> feature[:,128:256]
    int b = wid >> 7, o = wid & 127;
    const float* of1 = wsf + OF1O + b*512;
    float s = 0.f;
    #pragma unroll
    for (int i = 0; i < 8; ++i){ int k = lane + (i << 6); s = fmaf(of1[k], wg1[o*512 + k], s); }
    for (int off = 32; off; off >>= 1) s += __shfl_down(s, off);
    if (lane == 0) out[b*256 + 128 + o] = fmaxf(s + bg1[o], 0.f);
  } else if (wid < 2176){                            // group_output_feature -> feature[:,0:128]
    int o = wid - 2048;
    const float* gr1 = wsf + GR1O;
    float s = 0.f;
    #pragma unroll
    for (int i = 0; i < 8; ++i){ int k = lane + (i << 6); s = fmaf(gr1[k], wgr1[o*512 + k], s); }
    for (int off = 32; off; off >>= 1) s += __shfl_down(s, off);
    if (lane == 0){
      float r = fmaxf(s + bgr1[o], 0.f);
      for (int bb = 0; bb < 16; ++bb) out[bb*256 + o] = r;   // identical across batch
    }
  }
}

extern "C" void kernel_launch(void* const* d_in, const int* in_sizes, int n_in,
                              void* d_out, int out_size, void* d_ws, size_t ws_size,
                              hipStream_t stream)
{
  const float* pts  = (const float*)d_in[0];
  const float* wl0  = (const float*)d_in[1];  const float* bl0 = (const float*)d_in[2];
  const float* wl1  = (const float*)d_in[3];  const float* bl1 = (const float*)d_in[4];
  const float* wl2  = (const float*)d_in[5];  const float* bl2 = (const float*)d_in[6];
  const float* wl3  = (const float*)d_in[7];  const float* bl3 = (const float*)d_in[8];
  const float* wl4  = (const float*)d_in[9];  const float* bl4 = (const float*)d_in[10];
  const float* wg0  = (const float*)d_in[11]; const float* bg0 = (const float*)d_in[12];
  const float* wg1  = (const float*)d_in[13]; const float* bg1 = (const float*)d_in[14];
  const float* wgr0 = (const float*)d_in[15]; const float* bgr0 = (const float*)d_in[16];
  const float* wgr1 = (const float*)d_in[17]; const float* bgr1 = (const float*)d_in[18];
  float* wsf = (float*)d_ws;
  float* out = (float*)d_out;

  // ws-adaptive: pmax P slots (128 KB), gmax G slots (16 KB), Wb bf16x3 (768 KB)
  int P, G;
  if      (ws_size >= 2400000) { P = 8; G = 16; }   // 2.29 MB
  else if (ws_size >= 1700000) { P = 4; G = 8;  }   // 1.63 MB
  else if (ws_size >= 1360000) { P = 2; G = 4;  }   // 1.30 MB
  else                         { P = 1; G = 2;  }   // 1.14 MB
  u32 pmax_off = FIXED_BYTES;
  u32 gmax_off = pmax_off + (u32)P * 131072u;
  u32 wb_off   = gmax_off + (u32)G * 16384u;

  k_prep<<<dim3(1024), dim3(256), 0, stream>>>(wl0, wl1, wl2, wl3, wl4,
      bl0, bl1, bl2, bl3, bl4, wsf, pmax_off, gmax_off, wb_off, P, G);
  k_main<<<dim3(4096), dim3(256), 0, stream>>>(pts, wsf,
      (const u16b*)((char*)d_ws + wb_off),
      (u64*)((char*)d_ws + pmax_off), (u32*)((char*)d_ws + gmax_off), P-1, G-1);
  k_reduce<<<dim3(80), dim3(256), 0, stream>>>(wsf, out, pmax_off, gmax_off, P, G);
  k_mlp1<<<dim3(2176), dim3(256), 0, stream>>>(wsf, wg0, bg0, wgr0, bgr0);
  k_mlp2<<<dim3(544), dim3(256), 0, stream>>>(wsf, wg1, bg1, wgr1, bgr1, out);
}

// Round 10
// 644.112 us; speedup vs baseline: 1.9585x; 1.9585x over previous
//
#include <hip/hip_runtime.h>
#include <stdint.h>

typedef unsigned int u32;
typedef unsigned long long u64;
typedef unsigned short u16b;
typedef __attribute__((ext_vector_type(8))) short short8;   // 8 bf16 = 4 VGPR (MFMA A/B frag)
typedef __attribute__((ext_vector_type(4))) float v4f;      // MFMA C/D frag

constexpr int NP = 16384;   // points per batch
// ---- fixed float-region offsets (in floats) ----
constexpr int W0T = 0;        // [8][64]
constexpr int W1T = 512;      // [64][64]
constexpr int W2T = 4608;     // [64][64]
constexpr int W3T = 8704;     // [64][128]
constexpr int B0F = 16896, B1F = 16960, B2F = 17024, B3F = 17088, B4F = 17216;
constexpr int GFO = 18240;    // gf  [16][1024]
constexpr int GCFO = 34624;   // gcf [4][1024]
constexpr int OF1O = 38720;   // of1 [16][512]
constexpr int GR1O = 46912;   // gr1 [512]
constexpr int FIXED_FLOATS = 47424;
constexpr u32 FIXED_BYTES = FIXED_FLOATS * 4;   // 189696 B

struct __align__(16) f4 { float x, y, z, w; };

__device__ __forceinline__ u16b f2bf(float f){
  u32 u = __float_as_uint(f);
  return (u16b)((u + 0x7FFFu + ((u >> 16) & 1u)) >> 16);   // RNE
}
__device__ __forceinline__ float bfu(u16b h){ return __uint_as_float(((u32)h) << 16); }

// exact-cascade 3-way bf16 split: x ~= hi+mid+lo to ~27 bits
__device__ __forceinline__ void split3(float x, u16b& h, u16b& m, u16b& l){
  h = f2bf(x);           float r1 = x - bfu(h);
  m = f2bf(r1);          float r2 = r1 - bfu(m);
  l = f2bf(r2);
}

__device__ __forceinline__ void fma4(f4& c, float s, const f4& a){
  c.x = fmaf(s, a.x, c.x); c.y = fmaf(s, a.y, c.y);
  c.z = fmaf(s, a.z, c.z); c.w = fmaf(s, a.w, c.w);
}

// ---------------- prep: transpose L0-3 weights; split+frag-pack W5 to bf16x3 ----------------
// Wb layout (bf16): [s][kc][nt][lane][j]  addr = s*131072 + kc*32768 + nt*512 + L*8 + j
__global__ __launch_bounds__(256) void k_prep(
    const float* __restrict__ wl0, const float* __restrict__ wl1, const float* __restrict__ wl2,
    const float* __restrict__ wl3, const float* __restrict__ wl4,
    const float* __restrict__ bl0, const float* __restrict__ bl1, const float* __restrict__ bl2,
    const float* __restrict__ bl3, const float* __restrict__ bl4,
    float* __restrict__ wsf, u32 pmax_off, u32 gmax_off, u32 wb_off, int P, int G)
{
  int tid = blockIdx.x * 256 + threadIdx.x;            // grid 1024 -> 262144 threads
  u64* pmax = (u64*)((char*)wsf + pmax_off);
  u32* gmax = (u32*)((char*)wsf + gmax_off);
  if (tid < P * 16384) pmax[tid] = 0ull;
  if (tid < G * 4096)  gmax[tid] = 0u;
  if (tid < 131072){                                   // W5 split -> Wb
    int ch = tid >> 7, k = tid & 127;
    float x = wl4[tid];                                // wl4[ch*128 + k]
    u16b h, m, l; split3(x, h, m, l);
    int kc = k >> 5, q = (k >> 3) & 3, j = k & 7, nt = ch >> 4;
    u32 base = (u32)kc*32768u + (u32)nt*512u + (u32)(((ch & 15) | (q << 4)) * 8 + j);
    u16b* wb = (u16b*)((char*)wsf + wb_off);
    wb[base] = h; wb[131072u + base] = m; wb[262144u + base] = l;
  }
  if (tid < 512){ int k = tid >> 6, o = tid & 63;
    wsf[W0T + tid] = (k < 7) ? wl0[o*7 + k] : 0.f; }
  if (tid < 4096){ int k = tid >> 6, o = tid & 63;  wsf[W1T + tid] = wl1[o*64 + k]; }
  if (tid < 4096){ int k = tid >> 6, o = tid & 63;  wsf[W2T + tid] = wl2[o*64 + k]; }
  if (tid < 8192){ int k = tid >> 7, o = tid & 127; wsf[W3T + tid] = wl3[o*64 + k]; }
  if (tid < 64)   wsf[B0F + tid] = bl0[tid];
  if (tid < 64)   wsf[B1F + tid] = bl1[tid];
  if (tid < 64)   wsf[B2F + tid] = bl2[tid];
  if (tid < 128)  wsf[B3F + tid] = bl3[tid];
  if (tid < 1024) wsf[B4F + tid] = bl4[tid];
}

// 4pt x 4ch micro-tile for layers 0..3 (acts from LDS, weights from L2-resident ws)
template<int K, int OSTR>
__device__ __forceinline__ void gemm4(const float* Ain, const float* __restrict__ Wt,
                                      int pt4, int o4, f4 (&acc)[4])
{
  #pragma unroll
  for (int oi = 0; oi < 4; ++oi) acc[oi] = f4{0.f,0.f,0.f,0.f};
  #pragma unroll 4
  for (int k = 0; k < K; ++k){
    f4 a = *(const f4*)(Ain + k*64 + pt4);
    f4 w = *(const f4*)(Wt + k*OSTR + o4);
    fma4(acc[0], w.x, a); fma4(acc[1], w.y, a);
    fma4(acc[2], w.z, a); fma4(acc[3], w.w, a);
  }
}

__device__ __forceinline__ void epi4(const f4 (&acc)[4], const float* __restrict__ bias,
                                     int o4, float* out, int pt4)
{
  #pragma unroll
  for (int oi = 0; oi < 4; ++oi){
    float bb = bias[o4 + oi];
    f4 v = acc[oi];
    v.x = fmaxf(v.x + bb, 0.f); v.y = fmaxf(v.y + bb, 0.f);
    v.z = fmaxf(v.z + bb, 0.f); v.w = fmaxf(v.w + bb, 0.f);
    *(f4*)(out + (o4 + oi)*64 + pt4) = v;
  }
}

// split3 + frag-store of one L3 output half into F4 (LDS). Named-array ref at each
// call site. Slot swizzle S = Lf ^ m -> 8 banks x 2 lanes = conflict-free (verified:
// conflicts 1.1e7 -> 1.66e6 in r9); reads use L ^ m, a lane bijection.
template<int H>
__device__ __forceinline__ void storeF4(u16b* F4, const f4 (&acc)[4],
                                        int o4, int pt4, const float* __restrict__ wsf)
{
  const int kbase = o4 + 64*H;
  const int kc = kbase >> 5, q = (kbase >> 3) & 3, j0 = kbase & 7;
  #pragma unroll
  for (int jj = 0; jj < 4; ++jj){
    int pt = pt4 + jj;
    int m = pt >> 4, Lf = (pt & 15) | (q << 4);
    int SLf = Lf ^ m;                       // ^m swizzle (bank-spreading)
    u16b hh[4], mm[4], ll[4];
    #pragma unroll
    for (int oi = 0; oi < 4; ++oi){
      float v = fmaxf(((const float*)&acc[oi])[jj] + wsf[B3F + kbase + oi], 0.f);
      split3(v, hh[oi], mm[oi], ll[oi]);
    }
    u32 base = (u32)((m*4 + kc)*512 + SLf*8 + j0);
    #pragma unroll
    for (int s = 0; s < 3; ++s){
      const u16b* src = (s == 0) ? hh : (s == 1) ? mm : ll;
      uint2 pk;
      pk.x = (u32)src[0] | ((u32)src[1] << 16);
      pk.y = (u32)src[2] | ((u32)src[3] << 16);
      *(uint2*)(F4 + (u32)s*8192u + base) = pk;
    }
  }
}

// ---------------- fused local MLP: L0-3 fp32 VALU, L4 bf16-split3 MFMA ----------------
// Single 48 KB LDS buffer, region-multiplexed:
//   A0 [0,448)f + gmS @448f | A1/A3 @512f (16 KB) | A2 @4608f (16 KB) | F4 = whole buf (48 KB)
// __launch_bounds__(256,2): r8/r9's (256,3) VGPR cap triggered loop-invariant spill
// (FETCH 7MB -> 2.45GB, VGPR 120 -> 84). 48 KB LDS still admits 3 blocks/CU if VGPR<=170.
__global__ __launch_bounds__(256, 2) void k_main(const float* __restrict__ pts,
    const float* __restrict__ wsf,
    const u16b* __restrict__ wb,            // Wb split weights (global, L2-resident)
    u64* __restrict__ pmax, u32* __restrict__ gmax,
    int pmask, int gmask)
{
  __shared__ __align__(16) float sB[12288];    // 49152 B
  const int t = threadIdx.x;
  const int b = blockIdx.x >> 8;
  const int tile = blockIdx.x & 255;
  const int n0 = tile * 64;
  const int ptg = t & 15, pt4 = ptg << 2;
  const int chg = t >> 4;
  const int o4 = chg << 2;
  const int w = t >> 6;            // wave id 0..3
  const int L = t & 63;
  const int qb = (L >> 4) << 2;    // my D-row quad base

  u64* gmS = (u64*)(sB + 448);
  if (t < 4) gmS[t] = 0ull;
  for (int e = t; e < 7*64; e += 256)
    sB[e] = pts[(b*7 + (e >> 6))*NP + n0 + (e & 63)];
  __syncthreads();   // s1

  // per-point group id (argmax ch 3..6, first occurrence) -> 64-bit masks
  if (t < 64){
    float v = sB[3*64 + t]; int gi = 0;
    float u1 = sB[4*64 + t]; if (u1 > v){ v = u1; gi = 1; }
    float u2 = sB[5*64 + t]; if (u2 > v){ v = u2; gi = 2; }
    float u3 = sB[6*64 + t]; if (u3 > v){ v = u3; gi = 3; }
    atomicOr(&gmS[gi], 1ull << t);
  }

  f4 acc4[4];
  gemm4<7,64>(sB, wsf + W0T, pt4, o4, acc4);        // L0 reads A0 @0
  epi4(acc4, wsf + B0F, o4, sB + 512, pt4);         // A1 @512 (disjoint from A0)
  __syncthreads();   // s2 (A1 ready + masks done)

  // ggpack: 2-bit group id for each of my 16 D-slots (i = m*4+r -> pt = m*16+qb+r)
  u32 g1lo = (u32)gmS[1], g1hi = (u32)(gmS[1] >> 32);
  u32 g2lo = (u32)gmS[2], g2hi = (u32)(gmS[2] >> 32);
  u32 g3lo = (u32)gmS[3], g3hi = (u32)(gmS[3] >> 32);
  u32 ggpack = 0;
  #pragma unroll
  for (int i = 0; i < 16; ++i){
    int m = i >> 2, r = i & 3;
    int sh = ((m & 1) << 4) + qb + r;          // pt&31
    u32 b1 = ((m < 2 ? g1lo : g1hi) >> sh) & 1u;
    u32 b2 = ((m < 2 ? g2lo : g2hi) >> sh) & 1u;
    u32 b3 = ((m < 2 ? g3lo : g3hi) >> sh) & 1u;
    u32 g = b1 + (b2 << 1) + (b3 << 1) + b3;   // 0..3, one-hot source
    ggpack |= g << (2*i);
  }

  gemm4<64,64>(sB + 512, wsf + W1T, pt4, o4, acc4);  epi4(acc4, wsf + B1F, o4, sB + 4608, pt4);
  __syncthreads();   // s3 (A2 @4608)
  gemm4<64,64>(sB + 4608, wsf + W2T, pt4, o4, acc4); epi4(acc4, wsf + B2F, o4, sB + 512, pt4);
  __syncthreads();   // s4 (A3 @512)

  // L3: both halves into named register arrays (A3 stays readable), then barrier
  f4 acc4b[4];
  gemm4<64,128>(sB + 512, wsf + W3T, pt4, o4, acc4);        // ch o4..o4+3
  gemm4<64,128>(sB + 512, wsf + W3T, pt4, o4 + 64, acc4b);  // ch o4+64..
  __syncthreads();   // s5 (all A3 reads complete; F4 may overwrite everything)

  u16b* F4 = (u16b*)sB;   // [s][frag=m*4+kc][slot][j] : 3*16*64*8 bf16 = 48 KB
  storeF4<0>(F4, acc4,  o4, pt4, wsf);
  storeF4<1>(F4, acc4b, o4, pt4, wsf);
  __syncthreads();   // s6 (F4 ready)

  u64* pslot = pmax + (size_t)(tile & pmask)*(16*1024) + b*1024;
  u32* gslot = gmax + (size_t)(tile & gmask)*4096;
  const char* wbc = (const char*)wb;
  const u32 bvo = (u32)L * 16u;

  // ---- L4: 16 N-tiles/wave; 6-term split-3 MFMA; B-frags software-pipelined ----
  short8 bh, bm, bl;
  {
    u32 bofs = ((u32)(w << 4)) * 1024u + bvo;        // (nt = w*16, kc = 0)
    bh = *(const short8*)(wbc +           bofs);
    bm = *(const short8*)(wbc + 262144u + bofs);
    bl = *(const short8*)(wbc + 524288u + bofs);
  }
  for (int nti = 0; nti < 16; ++nti){
    const int nt = (w << 4) + nti;
    float bias = wsf[B4F + (nt << 4) + (L & 15)];    // issue early
    v4f D[4];
    #pragma unroll
    for (int m = 0; m < 4; ++m) D[m] = (v4f)(0.f);
    #pragma unroll
    for (int kc = 0; kc < 4; ++kc){
      short8 cbh = bh, cbm = bm, cbl = bl;
      // prefetch next stage (kc+1, wrapping to next nt; tail over-reads stay in Wb)
      {
        int knext = (kc == 3) ? 0 : kc + 1;
        int ntn   = (kc == 3) ? nt + 1 : nt;
        u32 bofs = (u32)knext*65536u + (u32)ntn*1024u + bvo;
        bh = *(const short8*)(wbc +           bofs);
        bm = *(const short8*)(wbc + 262144u + bofs);
        bl = *(const short8*)(wbc + 524288u + bofs);
      }
      #pragma unroll
      for (int m = 0; m < 4; ++m){
        const u16b* fb = F4 + (u32)((m*4 + kc)*512 + ((L ^ m) << 3));   // ^m swizzle
        short8 a0 = *(const short8*)(fb);
        short8 a1 = *(const short8*)(fb + 8192);
        short8 a2 = *(const short8*)(fb + 16384);
        D[m] = __builtin_amdgcn_mfma_f32_16x16x32_bf16(a0, cbh, D[m], 0, 0, 0);
        D[m] = __builtin_amdgcn_mfma_f32_16x16x32_bf16(a0, cbm, D[m], 0, 0, 0);
        D[m] = __builtin_amdgcn_mfma_f32_16x16x32_bf16(a1, cbh, D[m], 0, 0, 0);
        D[m] = __builtin_amdgcn_mfma_f32_16x16x32_bf16(a0, cbl, D[m], 0, 0, 0);
        D[m] = __builtin_amdgcn_mfma_f32_16x16x32_bf16(a1, cbm, D[m], 0, 0, 0);
        D[m] = __builtin_amdgcn_mfma_f32_16x16x32_bf16(a2, cbh, D[m], 0, 0, 0);
      }
    }
    // epilogue: bias+relu, per-lane argmax over 16 slots, group-masked maxes
    float mx = 0.f; int mi = 0;
    float gm0 = 0.f, gm1 = 0.f, gm2 = 0.f, gm3 = 0.f;
    #pragma unroll
    for (int m = 0; m < 4; ++m){
      #pragma unroll
      for (int r = 0; r < 4; ++r){
        int i = m*4 + r;
        float v = fmaxf(D[m][r] + bias, 0.f);
        int pidx = n0 + m*16 + qb + r;
        if (i == 0){ mx = v; mi = pidx; }
        else if (v > mx){ mx = v; mi = pidx; }
        u32 g = (ggpack >> (2*i)) & 3u;
        gm0 = fmaxf(gm0, (g == 0u) ? v : 0.f);
        gm1 = fmaxf(gm1, (g == 1u) ? v : 0.f);
        gm2 = fmaxf(gm2, (g == 2u) ? v : 0.f);
        gm3 = fmaxf(gm3, (g == 3u) ? v : 0.f);
      }
    }
    #pragma unroll
    for (int s = 16; s <= 32; s <<= 1){
      float m2 = __shfl_xor(mx, s);
      int  i2  = __shfl_xor(mi, s);
      if (m2 > mx || (m2 == mx && i2 < mi)){ mx = m2; mi = i2; }
      gm0 = fmaxf(gm0, __shfl_xor(gm0, s));
      gm1 = fmaxf(gm1, __shfl_xor(gm1, s));
      gm2 = fmaxf(gm2, __shfl_xor(gm2, s));
      gm3 = fmaxf(gm3, __shfl_xor(gm3, s));
    }
    if (L < 16){
      int ch = (nt << 4) + L;
      u64 pk = ((u64)__float_as_uint(mx) << 32) | (u64)(0xFFFFFFFFu - (u32)mi);
      atomicMax(pslot + ch, pk);
      if (gm0 > 0.f) atomicMax(gslot + ch,        __float_as_uint(gm0));
      if (gm1 > 0.f) atomicMax(gslot + 1024 + ch, __float_as_uint(gm1));
      if (gm2 > 0.f) atomicMax(gslot + 2048 + ch, __float_as_uint(gm2));
      if (gm3 > 0.f) atomicMax(gslot + 3072 + ch, __float_as_uint(gm3));
    }
  }
}

// ---------------- fold slots; emit max_indices (fp32) + gf + gcf ----------------
__global__ __launch_bounds__(256) void k_reduce(float* __restrict__ wsf, float* __restrict__ out,
                                                u32 pmax_off, u32 gmax_off, int P, int G)
{
  int e = blockIdx.x * 256 + threadIdx.x;          // grid 80 -> 20480
  u64* pmax = (u64*)((char*)wsf + pmax_off);
  u32* gmax = (u32*)((char*)wsf + gmax_off);
  if (e < 16384){
    u64 m = 0ull;
    for (int s = 0; s < P; ++s){ u64 v = pmax[s*16384 + e]; if (v > m) m = v; }
    float val = __uint_as_float((u32)(m >> 32));
    u32 idx = 0xFFFFFFFFu - (u32)(m & 0xFFFFFFFFull);
    wsf[GFO + e] = val;
    out[4096 + e] = (float)idx;                    // max_indices, fp32
  } else if (e < 20480){
    int e2 = e - 16384;
    u32 mg = 0u;
    for (int s = 0; s < G; ++s){ u32 v = gmax[s*4096 + e2]; if (v > mg) mg = v; }
    wsf[GCFO + e2] = __uint_as_float(mg);
  }
}

// ---------------- small MLPs: one wave per dot product ----------------
__global__ __launch_bounds__(256) void k_mlp1(float* __restrict__ wsf,
    const float* __restrict__ wg0, const float* __restrict__ bg0,
    const float* __restrict__ wgr0, const float* __restrict__ bgr0)
{
  int wid = (blockIdx.x * 256 + threadIdx.x) >> 6;   // grid 2176 -> 8704 waves
  int lane = threadIdx.x & 63;
  if (wid < 8192){                                   // of1 = relu(gf @ wg0^T + bg0)
    int b = wid >> 9, o = wid & 511;
    const float* gf = wsf + GFO + b*1024;
    float s = 0.f;
    #pragma unroll
    for (int i = 0; i < 16; ++i){ int k = lane + (i << 6); s = fmaf(gf[k], wg0[o*1024 + k], s); }
    for (int off = 32; off; off >>= 1) s += __shfl_down(s, off);
    if (lane == 0) wsf[OF1O + b*512 + o] = fmaxf(s + bg0[o], 0.f);
  } else if (wid < 8704){                            // gr1 = relu(gcf @ wgr0^T + bgr0)
    int o = wid - 8192;
    const float* gcf = wsf + GCFO;
    float s = 0.f;
    #pragma unroll 8
    for (int i = 0; i < 64; ++i){ int k = lane + (i << 6); s = fmaf(gcf[k], wgr0[o*4096 + k], s); }
    for (int off = 32; off; off >>= 1) s += __shfl_down(s, off);
    if (lane == 0) wsf[GR1O + o] = fmaxf(s + bgr0[o], 0.f);
  }
}

__global__ __launch_bounds__(256) void k_mlp2(const float* __restrict__ wsf,
    const float* __restrict__ wg1, const float* __restrict__ bg1,
    const float* __restrict__ wgr1, const float* __restrict__ bgr1,
    float* __restrict__ out)
{
  int wid = (blockIdx.x * 256 + threadIdx.x) >> 6;   // grid 544 -> 2176 waves
  int lane = threadIdx.x & 63;
  if (wid < 2048){                                   // output_feature -> feature[:,128:256]
    int b = wid >> 7, o = wid & 127;
    const float* of1 = wsf + OF1O + b*512;
    float s = 0.f;
    #pragma unroll
    for (int i = 0; i < 8; ++i){ int k = lane + (i << 6); s = fmaf(of1[k], wg1[o*512 + k], s); }
    for (int off = 32; off; off >>= 1) s += __shfl_down(s, off);
    if (lane == 0) out[b*256 + 128 + o] = fmaxf(s + bg1[o], 0.f);
  } else if (wid < 2176){                            // group_output_feature -> feature[:,0:128]
    int o = wid - 2048;
    const float* gr1 = wsf + GR1O;
    float s = 0.f;
    #pragma unroll
    for (int i = 0; i < 8; ++i){ int k = lane + (i << 6); s = fmaf(gr1[k], wgr1[o*512 + k], s); }
    for (int off = 32; off; off >>= 1) s += __shfl_down(s, off);
    if (lane == 0){
      float r = fmaxf(s + bgr1[o], 0.f);
      for (int bb = 0; bb < 16; ++bb) out[bb*256 + o] = r;   // identical across batch
    }
  }
}

extern "C" void kernel_launch(void* const* d_in, const int* in_sizes, int n_in,
                              void* d_out, int out_size, void* d_ws, size_t ws_size,
                              hipStream_t stream)
{
  const float* pts  = (const float*)d_in[0];
  const float* wl0  = (const float*)d_in[1];  const float* bl0 = (const float*)d_in[2];
  const float* wl1  = (const float*)d_in[3];  const float* bl1 = (const float*)d_in[4];
  const float* wl2  = (const float*)d_in[5];  const float* bl2 = (const float*)d_in[6];
  const float* wl3  = (const float*)d_in[7];  const float* bl3 = (const float*)d_in[8];
  const float* wl4  = (const float*)d_in[9];  const float* bl4 = (const float*)d_in[10];
  const float* wg0  = (const float*)d_in[11]; const float* bg0 = (const float*)d_in[12];
  const float* wg1  = (const float*)d_in[13]; const float* bg1 = (const float*)d_in[14];
  const float* wgr0 = (const float*)d_in[15]; const float* bgr0 = (const float*)d_in[16];
  const float* wgr1 = (const float*)d_in[17]; const float* bgr1 = (const float*)d_in[18];
  float* wsf = (float*)d_ws;
  float* out = (float*)d_out;

  // ws-adaptive: pmax P slots (128 KB), gmax G slots (16 KB), Wb bf16x3 (768 KB)
  int P, G;
  if      (ws_size >= 2400000) { P = 8; G = 16; }   // 2.29 MB
  else if (ws_size >= 1700000) { P = 4; G = 8;  }   // 1.63 MB
  else if (ws_size >= 1360000) { P = 2; G = 4;  }   // 1.30 MB
  else                         { P = 1; G = 2;  }   // 1.14 MB
  u32 pmax_off = FIXED_BYTES;
  u32 gmax_off = pmax_off + (u32)P * 131072u;
  u32 wb_off   = gmax_off + (u32)G * 16384u;

  k_prep<<<dim3(1024), dim3(256), 0, stream>>>(wl0, wl1, wl2, wl3, wl4,
      bl0, bl1, bl2, bl3, bl4, wsf, pmax_off, gmax_off, wb_off, P, G);
  k_main<<<dim3(4096), dim3(256), 0, stream>>>(pts, wsf,
      (const u16b*)((char*)d_ws + wb_off),
      (u64*)((char*)d_ws + pmax_off), (u32*)((char*)d_ws + gmax_off), P-1, G-1);
  k_reduce<<<dim3(80), dim3(256), 0, stream>>>(wsf, out, pmax_off, gmax_off, P, G);
  k_mlp1<<<dim3(2176), dim3(256), 0, stream>>>(wsf, wg0, bg0, wgr0, bgr0);
  k_mlp2<<<dim3(544), dim3(256), 0, stream>>>(wsf, wg1, bg1, wgr1, bgr1, out);
}